// Round 1
// baseline (507.466 us; speedup 1.0000x reference)
//
#include <hip/hip_runtime.h>
#include <cmath>

// NTM memory op: address (cosine softmax + interpolate + shift + sharpen),
// read r = w^T memory, write new_memory = memory*(1 - w e^T) + w a^T.
// B=128, N=8192, M=64, fp32. Three kernels, all stream-ordered.
//
// Traffic plan (unchanged from 507 µs baseline): memory (256 MiB) read twice
// (score, update), second read expected to hit L3; newmem written once with
// nontemporal stores. p = exp(beta*cos) staged in the not-yet-written newmem
// region of d_out; per-chunk partial sums staged in the r region, consumed
// then zeroed by weight_kernel before update_kernel's atomics accumulate r.
//
// This revision: 8-lanes-per-row retile (2x float4 per lane) in score/update
// -- halves per-byte load/addr-calc and cuts shuffle-reduce from 8 to 3
// swizzles per KB (3-stage instead of 4-stage chains). weight_kernel
// prefetches p/w_prev into registers before the serial partial-sum reduce.

namespace {
constexpr int B = 128;
constexpr int N = 8192;
constexpr int M = 64;
constexpr float F_EPS = 1e-16f;
constexpr float F_COS_EPS = 1e-8f;

constexpr int ROWS = 128;          // rows per block for kernels 1 & 3
constexpr int CHUNKS = N / ROWS;   // 64 chunks per batch
constexpr int T2 = 1024;           // threads for weight kernel
constexpr int PER = N / T2;        // 8 elements per thread
}

typedef float vfloat4 __attribute__((ext_vector_type(4)));

// ---------------------------------------------------------------------------
// Kernel 1: p[b][n] = exp(beta[b] * cosine(memory[b][n]+eps, k[b]+eps))
// (no max-subtraction: |score| <= ~1, exp can't overflow; softmax divides it
// out exactly). Also writes per-chunk partial sums of p into partial[b][chunk].
// Layout: 8 lanes per row, each lane holds float4 slots sub and sub+8.
// Wave = 8 rows per iteration (2 KB contiguous), 4 iterations = 32 rows.
// ---------------------------------------------------------------------------
__global__ __launch_bounds__(256) void score_kernel(
    const float* __restrict__ memory, const float* __restrict__ k,
    const float* __restrict__ beta, float* __restrict__ p_out,
    float* __restrict__ partial)
{
    const int b     = blockIdx.x / CHUNKS;
    const int chunk = blockIdx.x % CHUNKS;
    const int wave  = threadIdx.x >> 6;
    const int lane  = threadIdx.x & 63;
    const int grp   = lane >> 3;      // row within 8-row pack (0..7)
    const int sub   = lane & 7;       // float4 slot index (0..7), + 8 for hi

    const float4* k4 = reinterpret_cast<const float4*>(k + (size_t)b * M);
    const float4 kva = k4[sub];
    const float4 kvb = k4[sub + 8];
    const float4 kea = make_float4(kva.x + F_EPS, kva.y + F_EPS,
                                   kva.z + F_EPS, kva.w + F_EPS);
    const float4 keb = make_float4(kvb.x + F_EPS, kvb.y + F_EPS,
                                   kvb.z + F_EPS, kvb.w + F_EPS);
    float kn2 = kea.x*kea.x + kea.y*kea.y + kea.z*kea.z + kea.w*kea.w
              + keb.x*keb.x + keb.y*keb.y + keb.z*keb.z + keb.w*keb.w;
    #pragma unroll
    for (int m = 1; m <= 4; m <<= 1) kn2 += __shfl_xor(kn2, m, 64);
    const float knorm = sqrtf(kn2);
    const float bb = beta[b];

    const int row0 = chunk * ROWS + wave * (ROWS / 4);   // 32 rows per wave

    float psum = 0.0f;

    #pragma unroll
    for (int it = 0; it < 4; ++it) {
        const int row = row0 + it * 8 + grp;
        const float4* m4p =
            reinterpret_cast<const float4*>(memory + ((size_t)b * N + row) * M);
        const float4 mva = m4p[sub];
        const float4 mvb = m4p[sub + 8];
        const float4 mea = make_float4(mva.x + F_EPS, mva.y + F_EPS,
                                       mva.z + F_EPS, mva.w + F_EPS);
        const float4 meb = make_float4(mvb.x + F_EPS, mvb.y + F_EPS,
                                       mvb.z + F_EPS, mvb.w + F_EPS);
        float dot = mea.x*kea.x + mea.y*kea.y + mea.z*kea.z + mea.w*kea.w
                  + meb.x*keb.x + meb.y*keb.y + meb.z*keb.z + meb.w*keb.w;
        float n2  = mea.x*mea.x + mea.y*mea.y + mea.z*mea.z + mea.w*mea.w
                  + meb.x*meb.x + meb.y*meb.y + meb.z*meb.z + meb.w*meb.w;
        #pragma unroll
        for (int m = 1; m <= 4; m <<= 1) {
            dot += __shfl_xor(dot, m, 64);
            n2  += __shfl_xor(n2,  m, 64);
        }
        if (sub == 0) {
            const float denom = fmaxf(sqrtf(n2) * knorm, F_COS_EPS);
            const float pe = expf(bb * (dot / denom));
            p_out[(size_t)b * N + row] = pe;
            psum += pe;
        }
    }

    // psum is nonzero only on lanes 0,8,...,56; fold row-group bits into lane 0.
    psum += __shfl_xor(psum, 8, 64);
    psum += __shfl_xor(psum, 16, 64);
    psum += __shfl_xor(psum, 32, 64);

    __shared__ float ps[4];
    if (lane == 0) ps[wave] = psum;
    __syncthreads();
    if (threadIdx.x == 0)
        partial[b * CHUNKS + chunk] = ps[0] + ps[1] + ps[2] + ps[3];
}

// ---------------------------------------------------------------------------
// Kernel 2: one block (1024 thr) per batch. Normalize p -> softmax weight,
// interpolate with w_prev, circular 3-tap shift, pow(gamma), renormalize.
// Reads then zeroes the r region (which held the softmax partial sums).
// p/w_prev loads are issued into registers BEFORE the serial partial-sum
// reduce so their latency overlaps it.
// ---------------------------------------------------------------------------
__global__ __launch_bounds__(T2) void weight_kernel(
    const float* __restrict__ p, const float* __restrict__ g,
    const float* __restrict__ s, const float* __restrict__ gamma,
    const float* __restrict__ w_prev, float* __restrict__ w_out,
    float* __restrict__ r_out)
{
    const int b    = blockIdx.x;
    const int tid  = threadIdx.x;
    const int lane = tid & 63;
    const int wave = tid >> 6;

    __shared__ float wg[N];          // 32 KB
    __shared__ float red[T2 / 64];   // 16 waves
    __shared__ float sS;

    // Issue the big streaming loads first; latency overlaps the reduce below.
    float pv_r[PER], wp_r[PER];
    #pragma unroll
    for (int i = 0; i < PER; i++) {
        const int idx = tid + i * T2;
        pv_r[i] = p[(size_t)b * N + idx];
        wp_r[i] = w_prev[(size_t)b * N + idx];
    }

    // Sum the 64 per-chunk softmax partials (stored in the r region).
    if (tid < 64) {
        float v = r_out[(size_t)b * M + tid];
        #pragma unroll
        for (int m = 1; m <= 32; m <<= 1) v += __shfl_xor(v, m, 64);
        if (tid == 0) sS = v;
    }
    __syncthreads();
    const float invS = 1.0f / sS;

    // Zero the r accumulator region (consumed by update_kernel's atomics).
    if (tid < M) r_out[(size_t)b * M + tid] = 0.0f;

    const float gb  = g[b];
    const float gS  = gb * invS;
    const float gmb = 1.0f - gb;
    #pragma unroll
    for (int i = 0; i < PER; i++) {
        const int idx = tid + i * T2;
        wg[idx] = gS * pv_r[i] + gmb * wp_r[i];
    }
    __syncthreads();

    const float s0 = s[b * 3 + 0], s1 = s[b * 3 + 1], s2 = s[b * 3 + 2];
    const float gm = gamma[b];
    float pv[PER];
    float lsum = 0.0f;
    #pragma unroll
    for (int i = 0; i < PER; i++) {
        const int idx = tid + i * T2;
        const float sh = wg[(idx - 1) & (N - 1)] * s0
                       + wg[idx] * s1
                       + wg[(idx + 1) & (N - 1)] * s2;
        pv[i] = powf(sh, gm);
        lsum += pv[i];
    }
    #pragma unroll
    for (int m = 1; m <= 32; m <<= 1) lsum += __shfl_xor(lsum, m, 64);
    if (lane == 0) red[wave] = lsum;
    __syncthreads();
    float bsum = 0.0f;
    #pragma unroll
    for (int i = 0; i < T2 / 64; i++) bsum += red[i];
    const float invn = 1.0f / (bsum + F_EPS);

    #pragma unroll
    for (int i = 0; i < PER; i++) {
        const int idx = tid + i * T2;
        w_out[(size_t)b * N + idx] = pv[i] * invn;
    }
}

// ---------------------------------------------------------------------------
// Kernel 3: new_memory = memory*(1 - w e^T) + w a^T (nontemporal stores),
// fused with r[b][m] = sum_n w[b][n]*memory[b][n][m] (block partials +
// one atomicAdd per element per block). Same 8-lanes-per-row retile.
// ---------------------------------------------------------------------------
__global__ __launch_bounds__(256) void update_kernel(
    const float* __restrict__ memory, const float* __restrict__ e,
    const float* __restrict__ a, const float* __restrict__ w,
    float* __restrict__ newmem, float* __restrict__ r_out)
{
    const int b     = blockIdx.x / CHUNKS;
    const int chunk = blockIdx.x % CHUNKS;
    const int wave  = threadIdx.x >> 6;
    const int lane  = threadIdx.x & 63;
    const int grp   = lane >> 3;
    const int sub   = lane & 7;

    const float4* e4 = reinterpret_cast<const float4*>(e + (size_t)b * M);
    const float4* a4 = reinterpret_cast<const float4*>(a + (size_t)b * M);
    const float4 eva = e4[sub], evb = e4[sub + 8];
    const float4 ava = a4[sub], avb = a4[sub + 8];

    const int row0 = chunk * ROWS + wave * (ROWS / 4);   // 32 rows per wave

    float4 accA = make_float4(0.f, 0.f, 0.f, 0.f);
    float4 accB = make_float4(0.f, 0.f, 0.f, 0.f);

    #pragma unroll
    for (int it = 0; it < 4; ++it) {
        const int row = row0 + it * 8 + grp;
        const size_t off = ((size_t)b * N + row) * M;
        const float4* m4p = reinterpret_cast<const float4*>(memory + off);
        const float4 mva = m4p[sub];
        const float4 mvb = m4p[sub + 8];
        const float ww = w[(size_t)b * N + row];

        vfloat4 nva, nvb;
        nva.x = mva.x * (1.0f - ww * eva.x) + ww * ava.x;
        nva.y = mva.y * (1.0f - ww * eva.y) + ww * ava.y;
        nva.z = mva.z * (1.0f - ww * eva.z) + ww * ava.z;
        nva.w = mva.w * (1.0f - ww * eva.w) + ww * ava.w;
        nvb.x = mvb.x * (1.0f - ww * evb.x) + ww * avb.x;
        nvb.y = mvb.y * (1.0f - ww * evb.y) + ww * avb.y;
        nvb.z = mvb.z * (1.0f - ww * evb.z) + ww * avb.z;
        nvb.w = mvb.w * (1.0f - ww * evb.w) + ww * avb.w;
        __builtin_nontemporal_store(nva, (vfloat4*)(newmem + off) + sub);
        __builtin_nontemporal_store(nvb, (vfloat4*)(newmem + off) + sub + 8);

        accA.x += ww * mva.x;  accA.y += ww * mva.y;
        accA.z += ww * mva.z;  accA.w += ww * mva.w;
        accB.x += ww * mvb.x;  accB.y += ww * mvb.y;
        accB.z += ww * mvb.z;  accB.w += ww * mvb.w;
    }

    // Reduce across the 8 row-groups (lanes differing in bits 3,4,5).
    #pragma unroll
    for (int m = 8; m <= 32; m <<= 1) {
        accA.x += __shfl_xor(accA.x, m, 64);
        accA.y += __shfl_xor(accA.y, m, 64);
        accA.z += __shfl_xor(accA.z, m, 64);
        accA.w += __shfl_xor(accA.w, m, 64);
        accB.x += __shfl_xor(accB.x, m, 64);
        accB.y += __shfl_xor(accB.y, m, 64);
        accB.z += __shfl_xor(accB.z, m, 64);
        accB.w += __shfl_xor(accB.w, m, 64);
    }

    __shared__ float sred[4][M];
    if (grp == 0) {
        sred[wave][sub * 4 + 0] = accA.x;
        sred[wave][sub * 4 + 1] = accA.y;
        sred[wave][sub * 4 + 2] = accA.z;
        sred[wave][sub * 4 + 3] = accA.w;
        sred[wave][32 + sub * 4 + 0] = accB.x;
        sred[wave][32 + sub * 4 + 1] = accB.y;
        sred[wave][32 + sub * 4 + 2] = accB.z;
        sred[wave][32 + sub * 4 + 3] = accB.w;
    }
    __syncthreads();
    if (threadIdx.x < M) {
        const float v = sred[0][threadIdx.x] + sred[1][threadIdx.x]
                      + sred[2][threadIdx.x] + sred[3][threadIdx.x];
        atomicAdd(&r_out[(size_t)b * M + threadIdx.x], v);
    }
}

// ---------------------------------------------------------------------------
extern "C" void kernel_launch(void* const* d_in, const int* in_sizes, int n_in,
                              void* d_out, int out_size, void* d_ws, size_t ws_size,
                              hipStream_t stream) {
    const float* memory = (const float*)d_in[0];
    const float* k      = (const float*)d_in[1];
    const float* beta   = (const float*)d_in[2];
    const float* g      = (const float*)d_in[3];
    const float* s      = (const float*)d_in[4];
    const float* gamma  = (const float*)d_in[5];
    const float* w_prev = (const float*)d_in[6];
    const float* e      = (const float*)d_in[7];
    const float* a      = (const float*)d_in[8];

    float* out    = (float*)d_out;
    float* w_out  = out;                                  // [B, N]
    float* r_out  = out + (size_t)B * N;                  // [B, M]
    float* newmem = out + (size_t)B * N + (size_t)B * M;  // [B, N, M]

    // p = exp(scores) staged in the not-yet-written new_memory region;
    // softmax partial sums staged in the r region (B*CHUNKS == B*M).
    float* p       = newmem;
    float* partsum = r_out;

    const dim3 blk(256);
    const dim3 grid1(B * CHUNKS);

    score_kernel<<<grid1, blk, 0, stream>>>(memory, k, beta, p, partsum);
    weight_kernel<<<dim3(B), dim3(T2), 0, stream>>>(p, g, s, gamma,
                                                    w_prev, w_out, r_out);
    update_kernel<<<grid1, blk, 0, stream>>>(memory, e, a, w_out,
                                             newmem, r_out);
}